// Round 1
// baseline (46.030 us; speedup 1.0000x reference)
//
#include <hip/hip_runtime.h>

// Problem constants (match reference)
constexpr int   FILLUP   = -100;
constexpr float BASEP    = 0.2f / 3.0f;   // SMOOTHING / C
constexpr float CONF     = 0.8f;          // 1 - SMOOTHING
constexpr int   NB       = 2097152;       // B
constexpr int   TT       = 5;             // T
constexpr int   THREADS  = 256;
constexpr int   BPT      = 4;                         // batch rows per thread
constexpr int   NTHR     = NB / BPT;                  // 524288
constexpr int   NBLOCKS  = NTHR / THREADS;            // 2048

__global__ __launch_bounds__(THREADS)
void ce_lsr_stage1(const float* __restrict__ pred,
                   const int*  __restrict__ lab,
                   float* __restrict__ partial) {
    const int tid = blockIdx.x * THREADS + threadIdx.x;   // 0..NTHR-1

    // 4 rows * 15 floats = 60 floats = 15 float4 (16B-aligned: 240B/thread)
    const float4* p4 = reinterpret_cast<const float4*>(pred) + (size_t)tid * 15;
    // 4 rows * 5 ints = 20 ints = 5 int4 (80B/thread)
    const int4*   l4 = reinterpret_cast<const int4*>(lab) + (size_t)tid * 5;

    float x[60];
#pragma unroll
    for (int i = 0; i < 15; ++i) {
        const float4 v = p4[i];
        x[4*i+0] = v.x; x[4*i+1] = v.y; x[4*i+2] = v.z; x[4*i+3] = v.w;
    }
    int lb[20];
#pragma unroll
    for (int i = 0; i < 5; ++i) {
        const int4 v = l4[i];
        lb[4*i+0] = v.x; lb[4*i+1] = v.y; lb[4*i+2] = v.z; lb[4*i+3] = v.w;
    }

    float acc = 0.0f;
#pragma unroll
    for (int bb = 0; bb < BPT; ++bb) {
#pragma unroll
        for (int t = 0; t < TT; ++t) {
            const int   l  = lb[bb*5 + t];
            const float x0 = x[bb*15 + t];
            const float x1 = x[bb*15 + 5 + t];
            const float x2 = x[bb*15 + 10 + t];
            const float m   = fmaxf(fmaxf(x0, x1), x2);
            const float s   = __expf(x0 - m) + __expf(x1 - m) + __expf(x2 - m);
            const float lse = m + __logf(s);
            const float xl  = (l == 1) ? x1 : ((l == 2) ? x2 : x0);
            const float c   = lse - BASEP * (x0 + x1 + x2) - CONF * xl;
            acc += (l != FILLUP) ? c : 0.0f;   // predicated, no divergence cost
        }
    }

    // wave (64-lane) shuffle reduce
#pragma unroll
    for (int off = 32; off > 0; off >>= 1)
        acc += __shfl_down(acc, off, 64);

    __shared__ float wsum[THREADS / 64];
    const int lane = threadIdx.x & 63;
    const int wid  = threadIdx.x >> 6;
    if (lane == 0) wsum[wid] = acc;
    __syncthreads();
    if (threadIdx.x == 0) {
        float s = 0.0f;
#pragma unroll
        for (int w = 0; w < THREADS / 64; ++w) s += wsum[w];
        partial[blockIdx.x] = s;   // every slot written every call (ws poison-safe)
    }
}

__global__ __launch_bounds__(256)
void ce_lsr_stage2(const float* __restrict__ partial,
                   float* __restrict__ out) {
    float acc = 0.0f;
#pragma unroll
    for (int i = 0; i < NBLOCKS / 256; ++i)          // 8 values/thread
        acc += partial[i * 256 + threadIdx.x];
#pragma unroll
    for (int off = 32; off > 0; off >>= 1)
        acc += __shfl_down(acc, off, 64);

    __shared__ float wsum[4];
    const int lane = threadIdx.x & 63;
    const int wid  = threadIdx.x >> 6;
    if (lane == 0) wsum[wid] = acc;
    __syncthreads();
    if (threadIdx.x == 0) {
        const float s = wsum[0] + wsum[1] + wsum[2] + wsum[3];
        out[0] = s * (1.0f / (float)NB);
    }
}

extern "C" void kernel_launch(void* const* d_in, const int* in_sizes, int n_in,
                              void* d_out, int out_size, void* d_ws, size_t ws_size,
                              hipStream_t stream) {
    const float* pred = (const float*)d_in[0];   // [B, C, T] f32
    const int*   lab  = (const int*)d_in[1];     // [B, T] int (harness: integer -> int32)
    float* out     = (float*)d_out;              // scalar f32
    float* partial = (float*)d_ws;               // 2048 f32 scratch

    ce_lsr_stage1<<<NBLOCKS, THREADS, 0, stream>>>(pred, lab, partial);
    ce_lsr_stage2<<<1, 256, 0, stream>>>(partial, out);
}

// Round 2
// 37.835 us; speedup vs baseline: 1.2166x; 1.2166x over previous
//
#include <hip/hip_runtime.h>

// loss = mean_b sum_t [ valid * ( lse(x) - (S/C)*sum_c x_c - (1-S)*x_label ) ]
// Memory-bound: 125.8 MB pred (f32) + 41.9 MB labels (i32), one f32 out.

constexpr int   FILLUP  = -100;
constexpr float BASEP   = 0.2f / 3.0f;   // SMOOTHING / C
constexpr float CONF    = 0.8f;          // 1 - SMOOTHING
constexpr int   NB      = 2097152;       // B
constexpr int   THREADS = 256;
constexpr int   ROWS    = 512;                  // rows per block
constexpr int   NBLOCKS = NB / ROWS;            // 4096
constexpr int   PRED_F4 = ROWS * 15 / 4;        // 1920 float4 per chunk
constexpr int   LAB_I4  = ROWS * 5 / 4;         // 640 int4 per chunk

__global__ __launch_bounds__(THREADS)
void ce_lsr_stage1(const float4* __restrict__ pred4,
                   const int4*  __restrict__ lab4,
                   float* __restrict__ partial) {
    // 30 KB + 10 KB = 40 KB LDS -> 4 blocks/CU (16 waves/CU)
    __shared__ __align__(16) float predS[ROWS * 15];
    __shared__ __align__(16) int   labS[ROWS * 5];

    const int t = threadIdx.x;
    const size_t pbase = (size_t)blockIdx.x * PRED_F4;
    const size_t lbase = (size_t)blockIdx.x * LAB_I4;

    // Coalesced staging: lane-contiguous float4 -> 1 KB / wave-instruction
    float4* predS4 = reinterpret_cast<float4*>(predS);
#pragma unroll
    for (int i = 0; i < 8; ++i) {
        const int idx = i * THREADS + t;
        if (idx < PRED_F4) predS4[idx] = pred4[pbase + idx];   // i=7: half wave
    }
    int4* labS4 = reinterpret_cast<int4*>(labS);
#pragma unroll
    for (int i = 0; i < 3; ++i) {
        const int idx = i * THREADS + t;
        if (idx < LAB_I4) labS4[idx] = lab4[lbase + idx];      // i=2: half wave
    }
    __syncthreads();

    float acc = 0.0f;
#pragma unroll
    for (int rr = 0; rr < 2; ++rr) {
        const int r = t + rr * THREADS;          // LDS stride 15 dwords: 2-way = free
        const float* __restrict__ xr = &predS[r * 15];
        const int*   __restrict__ lr = &labS[r * 5];
#pragma unroll
        for (int tt = 0; tt < 5; ++tt) {
            const int   l  = lr[tt];
            const float x0 = xr[tt];
            const float x1 = xr[5 + tt];
            const float x2 = xr[10 + tt];
            const float m   = fmaxf(fmaxf(x0, x1), x2);
            const float s   = __expf(x0 - m) + __expf(x1 - m) + __expf(x2 - m);
            const float lse = m + __logf(s);
            const float xl  = (l == 1) ? x1 : ((l == 2) ? x2 : x0);
            const float c   = lse - BASEP * (x0 + x1 + x2) - CONF * xl;
            acc += (l != FILLUP) ? c : 0.0f;
        }
    }

    // wave (64) shuffle reduce, then cross-wave via LDS
#pragma unroll
    for (int off = 32; off > 0; off >>= 1)
        acc += __shfl_down(acc, off, 64);

    __shared__ float wsum[THREADS / 64];
    const int lane = t & 63;
    const int wid  = t >> 6;
    if (lane == 0) wsum[wid] = acc;
    __syncthreads();
    if (t == 0) {
        float s = 0.0f;
#pragma unroll
        for (int w = 0; w < THREADS / 64; ++w) s += wsum[w];
        partial[blockIdx.x] = s;   // every slot written every call
    }
}

__global__ __launch_bounds__(256)
void ce_lsr_stage2(const float* __restrict__ partial,
                   float* __restrict__ out) {
    float acc = 0.0f;
#pragma unroll
    for (int i = 0; i < NBLOCKS / 256; ++i)          // 16 values/thread
        acc += partial[i * 256 + threadIdx.x];
#pragma unroll
    for (int off = 32; off > 0; off >>= 1)
        acc += __shfl_down(acc, off, 64);

    __shared__ float wsum[4];
    const int lane = threadIdx.x & 63;
    const int wid  = threadIdx.x >> 6;
    if (lane == 0) wsum[wid] = acc;
    __syncthreads();
    if (threadIdx.x == 0) {
        const float s = wsum[0] + wsum[1] + wsum[2] + wsum[3];
        out[0] = s * (1.0f / (float)NB);
    }
}

extern "C" void kernel_launch(void* const* d_in, const int* in_sizes, int n_in,
                              void* d_out, int out_size, void* d_ws, size_t ws_size,
                              hipStream_t stream) {
    const float4* pred4 = (const float4*)d_in[0];  // [B, C, T] f32
    const int4*   lab4  = (const int4*)d_in[1];    // [B, T] int32
    float* out     = (float*)d_out;                // scalar f32
    float* partial = (float*)d_ws;                 // 4096 f32 scratch

    ce_lsr_stage1<<<NBLOCKS, THREADS, 0, stream>>>(pred4, lab4, partial);
    ce_lsr_stage2<<<1, 256, 0, stream>>>(partial, out);
}

// Round 3
// 33.186 us; speedup vs baseline: 1.3871x; 1.1401x over previous
//
#include <hip/hip_runtime.h>
#include <stdint.h>

// loss = mean_b sum_t [ valid * ( lse(x) - (S/C)*sum_c x_c - (1-S)*x_label ) ]
// Memory-bound: 125.8 MB pred (f32) + 41.9 MB labels (i32) -> one f32 out.
// Structure: double-buffered LDS chunks, global_load_lds (async DMA) prefetch
// of chunk k+1 issued before compute of chunk k -> VMEM queue never drains
// except once per block (1024 cold starts amortized over 8 chunks each).

constexpr int   FILLUP  = -100;
constexpr float BASEP   = 0.2f / 3.0f;   // SMOOTHING / C
constexpr float CONF    = 0.8f;          // 1 - SMOOTHING
constexpr int   NB      = 2097152;       // B
constexpr int   THREADS = 256;
constexpr int   CROWS   = 256;                    // rows per chunk
constexpr int   NCHUNK  = NB / CROWS;             // 8192
constexpr int   CPB     = 8;                      // chunks per block
constexpr int   NBLOCKS = NCHUNK / CPB;           // 1024 = 4/CU x 256 CU
constexpr int   PRED_CB = CROWS * 15 * 4;         // 15360 B per chunk
constexpr int   LAB_CB  = CROWS * 5 * 4;          // 5120 B per chunk
constexpr int   PRED_SLOTS = PRED_CB / 16;        // 960 x 16B
constexpr int   LAB_SLOTS  = LAB_CB / 16;         // 320 x 16B

__device__ __forceinline__ void gll16(const void* g, void* l) {
    // async global->LDS, width 16B; LDS dest = wave-uniform base + lane*16
    __builtin_amdgcn_global_load_lds(
        (const __attribute__((address_space(1))) void*)g,
        (__attribute__((address_space(3))) void*)l, 16, 0, 0);
}

__device__ __forceinline__ void stage_chunk(const char* __restrict__ predB,
                                            const char* __restrict__ labB,
                                            int chunk, char* predL, char* labL,
                                            int t) {
    const char* ps = predB + (size_t)chunk * PRED_CB;
    const char* ls = labB  + (size_t)chunk * LAB_CB;
#pragma unroll
    for (int i = 0; i < 4; ++i) {                 // 960 slots: 3.75 iters (wave-aligned mask)
        const int idx = i * THREADS + t;
        if (idx < PRED_SLOTS) gll16(ps + (size_t)idx * 16, predL + idx * 16);
    }
#pragma unroll
    for (int i = 0; i < 2; ++i) {                 // 320 slots: 1.25 iters
        const int idx = i * THREADS + t;
        if (idx < LAB_SLOTS) gll16(ls + (size_t)idx * 16, labL + idx * 16);
    }
}

__global__ __launch_bounds__(THREADS)
void ce_lsr_stage1(const char* __restrict__ predB,
                   const char* __restrict__ labB,
                   float* __restrict__ partial) {
    // 2 x (15360 + 5120) = 40960 B exactly -> 4 blocks/CU (16 waves)
    __shared__ __align__(16) char predS[2][PRED_CB];
    __shared__ __align__(16) char labS[2][LAB_CB];

    const int t = threadIdx.x;
    const int cbase = blockIdx.x * CPB;

    stage_chunk(predB, labB, cbase, predS[0], labS[0], t);   // cold start (once)
    __syncthreads();                                         // vmcnt(0) drain -> buf0 ready

    float acc = 0.0f;
    for (int k = 0; k < CPB; ++k) {
        const int cur = k & 1;
        if (k + 1 < CPB)                                     // prefetch BEFORE compute
            stage_chunk(predB, labB, cbase + k + 1, predS[cur ^ 1], labS[cur ^ 1], t);

        // compute chunk k: 1 row/thread; LDS row stride 15 dwords
        // (gcd(15,32)=1 -> 2-way bank aliasing across 64 lanes = free)
        const float* __restrict__ xr = (const float*)(predS[cur]) + t * 15;
        const int*   __restrict__ lr = (const int*)(labS[cur]) + t * 5;
#pragma unroll
        for (int tt = 0; tt < 5; ++tt) {
            const int   l  = lr[tt];
            const float x0 = xr[tt];
            const float x1 = xr[5 + tt];
            const float x2 = xr[10 + tt];
            const float m   = fmaxf(fmaxf(x0, x1), x2);
            const float s   = __expf(x0 - m) + __expf(x1 - m) + __expf(x2 - m);
            const float lse = m + __logf(s);
            const float xl  = (l == 1) ? x1 : ((l == 2) ? x2 : x0);
            const float c   = lse - BASEP * (x0 + x1 + x2) - CONF * xl;
            acc += (l != FILLUP) ? c : 0.0f;
        }
        __syncthreads();   // drains prefetch (k+1 ready) + protects buf reuse
    }

    // block reduce: wave shuffle, then cross-wave via reused staging LDS
#pragma unroll
    for (int off = 32; off > 0; off >>= 1)
        acc += __shfl_down(acc, off, 64);

    float* wsum = (float*)predS;          // safe: all LDS readers done (loop-end barrier)
    if ((t & 63) == 0) wsum[t >> 6] = acc;
    __syncthreads();
    if (t == 0)
        partial[blockIdx.x] = wsum[0] + wsum[1] + wsum[2] + wsum[3];
}

__global__ __launch_bounds__(256)
void ce_lsr_stage2(const float* __restrict__ partial,
                   float* __restrict__ out) {
    float acc = 0.0f;
#pragma unroll
    for (int i = 0; i < NBLOCKS / 256; ++i)          // 4 values/thread
        acc += partial[i * 256 + threadIdx.x];
#pragma unroll
    for (int off = 32; off > 0; off >>= 1)
        acc += __shfl_down(acc, off, 64);

    __shared__ float wsum[4];
    const int lane = threadIdx.x & 63;
    const int wid  = threadIdx.x >> 6;
    if (lane == 0) wsum[wid] = acc;
    __syncthreads();
    if (threadIdx.x == 0) {
        const float s = wsum[0] + wsum[1] + wsum[2] + wsum[3];
        out[0] = s * (1.0f / (float)NB);
    }
}

extern "C" void kernel_launch(void* const* d_in, const int* in_sizes, int n_in,
                              void* d_out, int out_size, void* d_ws, size_t ws_size,
                              hipStream_t stream) {
    const char* pred = (const char*)d_in[0];   // [B, C, T] f32
    const char* lab  = (const char*)d_in[1];   // [B, T] int32
    float* out     = (float*)d_out;            // scalar f32
    float* partial = (float*)d_ws;             // 1024 f32 scratch (fully rewritten per call)

    ce_lsr_stage1<<<NBLOCKS, THREADS, 0, stream>>>(pred, lab, partial);
    ce_lsr_stage2<<<1, 256, 0, stream>>>(partial, out);
}